// Round 3
// baseline (296.637 us; speedup 1.0000x reference)
//
#include <hip/hip_runtime.h>
#include <math.h>

#define B_N     16384
#define D_N     512
#define NPAIR   8192
#define NBUCKET 4096
#define CON_BLOCKS 512           // 16 pairs per block (16 waves)
#define ELEM_PER_THREAD 16       // B_N / 1024

__device__ __forceinline__ float wave_reduce(float v) {
    #pragma unroll
    for (int m = 32; m >= 1; m >>= 1) v += __shfl_xor(v, m, 64);
    return v;
}

__device__ __forceinline__ float dot4(float4 a, float4 b) {
    return a.x*b.x + a.y*b.y + a.z*b.z + a.w*b.w;
}

__device__ __forceinline__ int bucket_of(float t) {
    // exact: multiply by 2^12 (power of two), floor; monotone in t
    return min(max((int)(t * 4096.0f), 0), NBUCKET - 1);
}

__device__ __forceinline__ unsigned long long key_of(float t, int i) {
    // stable argsort(-t): j at-or-before i (j!=i)  <=>  key_j > key_i
    return (((unsigned long long)__float_as_uint(t)) << 14) |
           (unsigned long long)(B_N - 1 - i);
}

// ---------------------------------------------------------------------------
// Fused kernel, grid = 513 x 1024 threads.
//   block 0        : entire Cox + NLL on one CU (bucket sort, O(B * avg 4))
//   blocks 1..512  : contrastive term, 16 pairs/block, HBM-bound (100 MB)
// Block 0 (~10 us) hides under the con blocks (~16-20 us HBM floor).
// ---------------------------------------------------------------------------
__global__ __launch_bounds__(1024) void k_fused(
        const float* __restrict__ rep1,
        const float* __restrict__ rep2,
        const float* __restrict__ rep3,
        const float* __restrict__ hazard,
        const float* __restrict__ score,
        const float* __restrict__ time,
        const int*   __restrict__ event,
        const int*   __restrict__ x1_idx,
        const int*   __restrict__ x2_idx,
        float* __restrict__ partCon,      // [512]
        float* __restrict__ scal,         // [0]=cox [1]=nll [2]=ev
        unsigned long long* __restrict__ skey,   // [B_N] scatter buffer
        float* __restrict__ sev)                 // [B_N]
{
    __shared__ int   cntB[NBUCKET];      // counts -> pos_excl -> bucket ends
    __shared__ float sumB[NBUCKET];      // expsums -> cumH (strictly-greater suffix)
    __shared__ int   sci[1024];
    __shared__ float scf[1024];
    __shared__ float wsum[48];

    const int tid  = threadIdx.x;
    const int lane = tid & 63;
    const int wave = tid >> 6;

    if (blockIdx.x != 0) {
        // ------------------ contrastive term ------------------
        const int p  = (blockIdx.x - 1) * 16 + wave;
        const int ia = x1_idx[p];
        const int ib = x2_idx[p];
        const float4* A1 = (const float4*)(rep1 + (size_t)ia * D_N);
        const float4* A2 = (const float4*)(rep2 + (size_t)ia * D_N);
        const float4* A3 = (const float4*)(rep3 + (size_t)ia * D_N);
        const float4* B1 = (const float4*)(rep1 + (size_t)ib * D_N);
        const float4* B2 = (const float4*)(rep2 + (size_t)ib * D_N);
        const float4* B3 = (const float4*)(rep3 + (size_t)ib * D_N);

        float v[15];
        #pragma unroll
        for (int k = 0; k < 15; ++k) v[k] = 0.f;

        #pragma unroll
        for (int r = 0; r < 2; ++r) {
            const int k = lane + r * 64;           // 128 float4 per row
            float4 a1 = A1[k], a2 = A2[k], a3 = A3[k];
            float4 b1 = B1[k], b2 = B2[k], b3 = B3[k];
            v[0]  += dot4(a1, a1); v[1]  += dot4(a2, a2); v[2]  += dot4(a3, a3);
            v[3]  += dot4(b1, b1); v[4]  += dot4(b2, b2); v[5]  += dot4(b3, b3);
            v[6]  += dot4(a1, a2); v[7]  += dot4(a1, a3); v[8]  += dot4(a2, a3);
            v[9]  += dot4(b1, b2); v[10] += dot4(b1, b3); v[11] += dot4(b2, b3);
            v[12] += dot4(a1, b1); v[13] += dot4(a2, b2); v[14] += dot4(a3, b3);
        }
        #pragma unroll
        for (int k = 0; k < 15; ++k) v[k] = wave_reduce(v[k]);

        if (lane == 0) {
            float n1a = fmaxf(sqrtf(v[0]), 1e-8f), n2a = fmaxf(sqrtf(v[1]), 1e-8f), n3a = fmaxf(sqrtf(v[2]), 1e-8f);
            float n1b = fmaxf(sqrtf(v[3]), 1e-8f), n2b = fmaxf(sqrtf(v[4]), 1e-8f), n3b = fmaxf(sqrtf(v[5]), 1e-8f);
            float dxx = v[6]/(n1a*n2a) + v[7]/(n1a*n3a) + v[8]/(n2a*n3a);
            float dyy = v[9]/(n1b*n2b) + v[10]/(n1b*n3b) + v[11]/(n2b*n3b);
            float dxy = v[12]/(n1a*n1b) + v[13]/(n2a*n2b) + v[14]/(n3a*n3b);
            float s = 0.2f + dxy - 0.5f*dxx - 0.5f*dyy;
            wsum[wave] = log1pf(expf(s));
        }
        __syncthreads();
        if (tid == 0) {
            float t = 0.f;
            #pragma unroll
            for (int w = 0; w < 16; ++w) t += wsum[w];
            partCon[blockIdx.x - 1] = t;
        }
        return;
    }

    // ------------------ Cox + NLL, single workgroup ------------------
    // Phase A: zero histogram
    #pragma unroll
    for (int b = tid; b < NBUCKET; b += 1024) { cntB[b] = 0; sumB[b] = 0.f; }
    __syncthreads();

    // Phase B: histogram + cache (t, e) per element
    float tc[ELEM_PER_THREAD], ec[ELEM_PER_THREAD];
    #pragma unroll
    for (int k = 0; k < ELEM_PER_THREAD; ++k) {
        const int i = tid + k * 1024;
        const float t = time[i];
        const float e = __expf(hazard[i]);
        tc[k] = t; ec[k] = e;
        const int b = bucket_of(t);
        atomicAdd(&cntB[b], 1);
        atomicAdd(&sumB[b], e);
    }
    __syncthreads();

    // Phase C: block scans. Thread tid owns buckets [tid*4, tid*4+4).
    int   c[4]; int   s  = 0;
    float f[4]; float fs = 0.f;
    #pragma unroll
    for (int k = 0; k < 4; ++k) {
        c[k] = cntB[tid * 4 + k];
        f[k] = sumB[tid * 4 + k];
    }
    int cex[4];
    #pragma unroll
    for (int k = 0; k < 4; ++k) { cex[k] = s; s += c[k]; fs += f[k]; }
    sci[tid] = s;
    scf[tid] = fs;
    __syncthreads();
    for (int d = 1; d < 1024; d <<= 1) {
        int   vi = (tid >= d) ? sci[tid - d] : 0;
        float vf = (tid >= d) ? scf[tid - d] : 0.f;
        __syncthreads();
        sci[tid] += vi;
        scf[tid] += vf;
        __syncthreads();
    }
    const int   ebase = sci[tid] - s;          // exclusive prefix of counts
    const float ftot  = scf[1023];
    float run = ftot - scf[tid];               // sum of exp over buckets after my chunk
    #pragma unroll
    for (int k = 0; k < 4; ++k) cntB[tid * 4 + k] = ebase + cex[k];   // pos_excl
    #pragma unroll
    for (int k = 3; k >= 0; --k) { sumB[tid * 4 + k] = run; run += f[k]; }  // cumH
    __syncthreads();

    // Phase D: counting scatter into global (L2-resident) key/exp arrays
    #pragma unroll
    for (int k = 0; k < ELEM_PER_THREAD; ++k) {
        const int i = tid + k * 1024;
        const int b = bucket_of(tc[k]);
        const int p = atomicAdd(&cntB[b], 1);
        skey[p] = key_of(tc[k], i);
        sev[p]  = ec[k];
    }
    __syncthreads();   // cntB[b] now holds end-offset of bucket b; writes visible

    // Phase E: per-element in-bucket correction + NLL
    float cox_p = 0.f, nll_p = 0.f, ev_p = 0.f;
    #pragma unroll
    for (int k = 0; k < ELEM_PER_THREAD; ++k) {
        const int i = tid + k * 1024;
        const int b = bucket_of(tc[k]);
        const unsigned long long ki = key_of(tc[k], i);
        const int lo = (b == 0) ? 0 : cntB[b - 1];
        const int hi = cntB[b];
        float cum = sumB[b] + ec[k];           // strictly-greater buckets + self
        for (int q = lo; q < hi; ++q) {
            if (skey[q] > ki) cum += sev[q];
        }
        const int ev = event[i];
        if (ev) cox_p += hazard[i] - logf(cum + 1e-6f);
        nll_p += score[i * 2 + ev];
        ev_p  += (float)ev;
    }

    // Phase F: block reduction -> scalars
    cox_p = wave_reduce(cox_p);
    nll_p = wave_reduce(nll_p);
    ev_p  = wave_reduce(ev_p);
    if (lane == 0) {
        wsum[wave]      = cox_p;
        wsum[16 + wave] = nll_p;
        wsum[32 + wave] = ev_p;
    }
    __syncthreads();
    if (tid == 0) {
        float X = 0.f, N = 0.f, E = 0.f;
        #pragma unroll
        for (int w = 0; w < 16; ++w) {
            X += wsum[w]; N += wsum[16 + w]; E += wsum[32 + w];
        }
        scal[0] = X; scal[1] = N; scal[2] = E;
    }
}

// ---------------------------------------------------------------------------
// Final reduction: 512 con partials + 3 scalars -> loss
// ---------------------------------------------------------------------------
__global__ __launch_bounds__(256) void k_final(const float* __restrict__ partCon,
                                               const float* __restrict__ scal,
                                               float* __restrict__ out)
{
    __shared__ float sh[4];
    const int tid  = threadIdx.x;
    const int lane = tid & 63;
    const int wave = tid >> 6;

    float con = partCon[tid] + partCon[tid + 256];
    con = wave_reduce(con);
    if (lane == 0) sh[wave] = con;
    __syncthreads();
    if (tid == 0) {
        float C = sh[0] + sh[1] + sh[2] + sh[3];
        float X = scal[0], N = scal[1], E = scal[2];
        float nll_t = -N / (float)B_N;
        float cox_t = -X / (E + 1e-6f);
        float con_t = C / (float)NPAIR;
        out[0] = nll_t + cox_t + 0.3f * con_t;
    }
}

extern "C" void kernel_launch(void* const* d_in, const int* in_sizes, int n_in,
                              void* d_out, int out_size, void* d_ws, size_t ws_size,
                              hipStream_t stream)
{
    const float* rep1   = (const float*)d_in[0];
    const float* rep2   = (const float*)d_in[1];
    const float* rep3   = (const float*)d_in[2];
    const float* hazard = (const float*)d_in[3];
    const float* score  = (const float*)d_in[4];
    const float* time_  = (const float*)d_in[5];
    const int*   event  = (const int*)d_in[6];
    const int*   x1     = (const int*)d_in[7];
    const int*   x2     = (const int*)d_in[8];
    float* out = (float*)d_out;

    char* w = (char*)d_ws;
    float* partCon = (float*)(w);                           // 512 floats
    float* scal    = (float*)(w + 2048);                    // 3 floats
    unsigned long long* skey = (unsigned long long*)(w + 4096);  // 128 KB
    float* sev     = (float*)(w + 4096 + B_N * 8);          // 64 KB
    // every ws slot used is written before read each call -> no memset node

    k_fused <<<CON_BLOCKS + 1, 1024, 0, stream>>>(rep1, rep2, rep3,
                                                  hazard, score, time_, event,
                                                  x1, x2, partCon, scal, skey, sev);
    k_final <<<1, 256, 0, stream>>>(partCon, scal, out);
}